// Round 6
// baseline (10947.939 us; speedup 1.0000x reference)
//
#include <hip/hip_runtime.h>

typedef unsigned int   u32;
typedef unsigned long long u64;

// ---------------- helpers ----------------
__device__ __forceinline__ float fast_tanh(float x) {
    x = fminf(fmaxf(x, -15.f), 15.f);
    float e = __expf(2.f * x);
    return __fdividef(e - 1.f, e + 1.f);
}

// ---------------- workspace layout (bytes) ----------------
#define OF_XG0  ((size_t)0)
#define OF_XG1  (OF_XG0 + 3276800)
#define OF_H0   (OF_XG1 + 3276800)
#define OF_H1   (OF_H0  + 1638400)
#define OF_PQ   (OF_H1  + 1638400)
#define OF_U    (OF_PQ  + 3276800)
#define OF_FLG  (OF_U   + 1638400)
// flags: [0..3] xg0 t-blocks (target 50), [4..7] xg1 t-blocks (target 50),
//        [8] PQ count (target 200), [9..12] U t-blocks (target 25)

// poll-read 4 consecutive hV elems (t, k..k+3), k%4==0, from a tagged 2-dir hist buffer.
// fwd (k<400): slot [t*400+k], tag t+1. bwd: slot [102400+(255-t)*400+k-400], tag 256-t.
__device__ __forceinline__ float4 hist4_poll(const u64* __restrict__ h, int t, int k) {
    const u64* p;
    u32 want;
    if (k < 400) { p = h + (size_t)t * 400 + k;                         want = (u32)(t + 1); }
    else         { p = h + 102400 + (size_t)(255 - t) * 400 + (k - 400); want = (u32)(256 - t); }
    for (;;) {
        u64 a = __hip_atomic_load(p + 0, __ATOMIC_RELAXED, __HIP_MEMORY_SCOPE_AGENT);
        u64 b = __hip_atomic_load(p + 1, __ATOMIC_RELAXED, __HIP_MEMORY_SCOPE_AGENT);
        u64 c = __hip_atomic_load(p + 2, __ATOMIC_RELAXED, __HIP_MEMORY_SCOPE_AGENT);
        u64 d = __hip_atomic_load(p + 3, __ATOMIC_RELAXED, __HIP_MEMORY_SCOPE_AGENT);
        if ((u32)(a >> 32) == want && (u32)(b >> 32) == want &&
            (u32)(c >> 32) == want && (u32)(d >> 32) == want)
            return make_float4(__uint_as_float((u32)a), __uint_as_float((u32)b),
                               __uint_as_float((u32)c), __uint_as_float((u32)d));
    }
}

__device__ __forceinline__ void stage_tile(float (*As)[68], float (*Bs)[68],
                                           int lr, int lk, float4 av, float4 bv) {
    As[lk + 0][lr] = av.x; As[lk + 1][lr] = av.y; As[lk + 2][lr] = av.z; As[lk + 3][lr] = av.w;
    Bs[lk + 0][lr] = bv.x; Bs[lk + 1][lr] = bv.y; Bs[lk + 2][lr] = bv.z; Bs[lk + 3][lr] = bv.w;
}

__device__ __forceinline__ void mac_tile(const float (*As)[68], const float (*Bs)[68],
                                         int ty, int tx, float acc[4][4]) {
#pragma unroll
    for (int kk = 0; kk < 16; ++kk) {
        float4 a4 = *(const float4*)&As[kk][ty * 4];
        float4 b4 = *(const float4*)&Bs[kk][tx * 4];
        acc[0][0] += a4.x*b4.x; acc[0][1] += a4.x*b4.y; acc[0][2] += a4.x*b4.z; acc[0][3] += a4.x*b4.w;
        acc[1][0] += a4.y*b4.x; acc[1][1] += a4.y*b4.y; acc[1][2] += a4.y*b4.z; acc[1][3] += a4.y*b4.w;
        acc[2][0] += a4.z*b4.x; acc[2][1] += a4.z*b4.y; acc[2][2] += a4.z*b4.z; acc[2][3] += a4.z*b4.w;
        acc[3][0] += a4.w*b4.x; acc[3][1] += a4.w*b4.y; acc[3][2] += a4.w*b4.z; acc[3][3] += a4.w*b4.w;
    }
}

__device__ __forceinline__ void publish(u32* flag, int tid) {
    __threadfence();           // release all this block's stores to agent scope
    __syncthreads();
    if (tid == 0)
        __hip_atomic_fetch_add(flag, 1u, __ATOMIC_RELAXED, __HIP_MEMORY_SCOPE_AGENT);
}

__device__ __forceinline__ void wait_flag(const u32* flag, u32 target) {
    while (__hip_atomic_load(flag, __ATOMIC_ACQUIRE, __HIP_MEMORY_SCOPE_AGENT) < target) {}
}

// ---------------- LSTM role (R4/R5-proven structure) ----------------
// 100 blocks/layer; block idx -> (d = idx/50, wg = idx%50) owns h-slice [wg*8, wg*8+8).
// Weights in registers; coop poll of tagged hist into double-buffered LDS; 1 barrier/step.
__device__ void lstm_role(char* smem, int idx,
                          const float* __restrict__ Whh, const float* __restrict__ h0,
                          const float* __restrict__ c0, int hc_base,
                          const float* __restrict__ xg, u64* __restrict__ hist,
                          const u32* __restrict__ xg_flags) {
    const int T = 256;
    float (*hbuf)[416] = (float(*)[416])smem;
    int d  = idx / 50;
    int wg = idx % 50;
    int a8 = wg * 8;
    int tid = threadIdx.x;
    int w = tid >> 6, lane = tid & 63;
    int c = lane & 7, r = lane >> 3;
    int gate = r >> 1, jj = r & 1;
    int gr = gate * 400 + a8 + 2 * w + jj;

    float4 wv[13];
    const float* wrow = Whh + (size_t)d * 640000 + (size_t)gr * 400;
#pragma unroll
    for (int i = 0; i < 13; ++i) {
        int k = 4 * (c + 8 * i);
        wv[i] = (k + 3 < 400) ? *(const float4*)(wrow + k) : make_float4(0.f, 0.f, 0.f, 0.f);
    }
    if (tid < 16) { hbuf[0][400 + tid] = 0.f; hbuf[1][400 + tid] = 0.f; }

    float c_state = 0.f;
    if (lane == 0 || lane == 8)
        c_state = c0[(hc_base + d) * 400 + a8 + 2 * w + jj];

    u64* hst = hist + (size_t)d * 102400;
    bool need2 = (tid + 256 < 400);
    u32 seen = 0;

    for (int t = 0; t < T; ++t) {
        int xt = d ? (T - 1 - t) : t;
        int tb = xt >> 6;
        if (!((seen >> tb) & 1)) {          // gate on xg tile readiness (4 polls total)
            wait_flag(&xg_flags[tb], 50u);
            seen |= 1u << tb;
        }
        float xgv = xg[(size_t)xt * 3200 + d * 1600 + gr];
        float* hb = hbuf[t & 1];

        if (t == 0) {
            hb[tid] = h0[(hc_base + d) * 400 + tid];
            if (need2) hb[tid + 256] = h0[(hc_base + d) * 400 + tid + 256];
        } else {
            const u64* src = hst + (size_t)(t - 1) * 400;
            u32 want = (u32)t;
            bool d1 = false, d2 = !need2;
            while (!(d1 && d2)) {
                u64 v1 = 0, v2 = 0;
                if (!d1) v1 = __hip_atomic_load(&src[tid], __ATOMIC_RELAXED, __HIP_MEMORY_SCOPE_AGENT);
                if (!d2) v2 = __hip_atomic_load(&src[tid + 256], __ATOMIC_RELAXED, __HIP_MEMORY_SCOPE_AGENT);
                if (!d1 && (u32)(v1 >> 32) == want) { hb[tid] = __uint_as_float((u32)v1); d1 = true; }
                if (!d2 && (u32)(v2 >> 32) == want) { hb[tid + 256] = __uint_as_float((u32)v2); d2 = true; }
            }
        }
        __syncthreads();

        const float4* h4 = (const float4*)hb;
        float s = 0.f;
#pragma unroll
        for (int i = 0; i < 13; ++i) {
            float4 hv = h4[c + 8 * i];
            s += wv[i].x * hv.x + wv[i].y * hv.y + wv[i].z * hv.z + wv[i].w * hv.w;
        }
        s += __shfl_down(s, 4);
        s += __shfl_down(s, 2);
        s += __shfl_down(s, 1);

        float v = 0.f;
        if (c == 0) {
            float tot = s + xgv;
            float arg = (gate == 2) ? 2.f * tot : -tot;
            arg = fminf(fmaxf(arg, -60.f), 60.f);
            float e = __expf(arg);
            v = (gate == 2) ? (e - 1.f) * __frcp_rn(e + 1.f)
                            : __frcp_rn(1.f + e);
        }
        float fv = __shfl(v, lane + 16);
        float gv = __shfl(v, lane + 32);
        float ov = __shfl(v, lane + 48);
        if (lane == 0 || lane == 8) {
            c_state = fv * c_state + v * gv;
            float ec = __expf(fminf(fmaxf(2.f * c_state, -60.f), 60.f));
            float th = (ec - 1.f) * __frcp_rn(ec + 1.f);
            float h = ov * th;
            u64 pk = (((u64)(t + 1)) << 32) | (u64)__float_as_uint(h);
            __hip_atomic_store(&hst[(size_t)t * 400 + a8 + 2 * w + jj], pk,
                               __ATOMIC_RELAXED, __HIP_MEMORY_SCOPE_AGENT);
        }
    }
}

// ---------------- the whole network in one kernel ----------------
__global__ __launch_bounds__(256, 5)
void mega_kernel(const int* __restrict__ words, const int* __restrict__ tags,
                 const int* __restrict__ arcs,
                 const float* __restrict__ h0, const float* __restrict__ c0,
                 const float* __restrict__ wemb, const float* __restrict__ temb,
                 const float* __restrict__ Wih0, const float* __restrict__ Whh0,
                 const float* __restrict__ bih0, const float* __restrict__ bhh0,
                 const float* __restrict__ Wih1, const float* __restrict__ Whh1,
                 const float* __restrict__ bih1, const float* __restrict__ bhh1,
                 const float* __restrict__ Wa1, const float* __restrict__ ba1,
                 const float* __restrict__ Wa2, const float* __restrict__ ba2,
                 const float* __restrict__ Wl1, const float* __restrict__ bl1,
                 const float* __restrict__ Wl2, const float* __restrict__ bl2,
                 float* __restrict__ xg0, float* __restrict__ xg1,
                 u64* __restrict__ hist0, u64* __restrict__ hist1,
                 float* __restrict__ PQ, float* __restrict__ Ub,
                 u32* __restrict__ flags, float* __restrict__ out) {
    extern __shared__ char smem[];
    int bid = blockIdx.x;
    int tid = threadIdx.x;

    if (bid < 200) {
        // ---- role: embed GEMM -> xg0 ----
        float (*As)[68] = (float(*)[68])smem;
        float (*Bs)[68] = (float(*)[68])(smem + 4352);
        int tb = bid & 3, t0 = tb * 64, n0 = (bid >> 2) * 64;
        int tx = tid & 15, ty = tid >> 4, lr = tid >> 2, lk = (tid & 3) * 4;
        float acc[4][4] = {};
        int t = t0 + lr;
        const float* arow0 = wemb + (size_t)words[t] * 300;
        const float* arow1 = temb + (size_t)tags[t] * 100 - 300;
        for (int k0 = 0; k0 < 400; k0 += 16) {
            int k = k0 + lk;
            float4 av = (k < 300) ? *(const float4*)(arow0 + k) : *(const float4*)(arow1 + k);
            float4 bv = *(const float4*)(Wih0 + (size_t)(n0 + lr) * 400 + k);
            __syncthreads();
            stage_tile(As, Bs, lr, lk, av, bv);
            __syncthreads();
            mac_tile(As, Bs, ty, tx, acc);
        }
        for (int i = 0; i < 4; ++i) {
            int tr = t0 + ty * 4 + i;
            float4 o;
            o.x = acc[i][0] + bih0[n0 + tx*4 + 0] + bhh0[n0 + tx*4 + 0];
            o.y = acc[i][1] + bih0[n0 + tx*4 + 1] + bhh0[n0 + tx*4 + 1];
            o.z = acc[i][2] + bih0[n0 + tx*4 + 2] + bhh0[n0 + tx*4 + 2];
            o.w = acc[i][3] + bih0[n0 + tx*4 + 3] + bhh0[n0 + tx*4 + 3];
            *(float4*)(xg0 + (size_t)tr * 3200 + n0 + tx * 4) = o;
        }
        publish(&flags[tb], tid);

    } else if (bid < 300) {
        // ---- role: LSTM layer 0 ----
        lstm_role(smem, bid - 200, Whh0, h0, c0, 0, xg0, hist0, &flags[0]);

    } else if (bid < 500) {
        // ---- role: GEMM hist0 -> xg1 (per-element tag polling) ----
        float (*As)[68] = (float(*)[68])smem;
        float (*Bs)[68] = (float(*)[68])(smem + 4352);
        int j = bid - 300;
        int tb = j & 3, t0 = tb * 64, n0 = (j >> 2) * 64;
        int tx = tid & 15, ty = tid >> 4, lr = tid >> 2, lk = (tid & 3) * 4;
        float acc[4][4] = {};
        int t = t0 + lr;
        for (int k0 = 0; k0 < 800; k0 += 16) {
            float4 av = hist4_poll(hist0, t, k0 + lk);
            float4 bv = *(const float4*)(Wih1 + (size_t)(n0 + lr) * 800 + k0 + lk);
            __syncthreads();
            stage_tile(As, Bs, lr, lk, av, bv);
            __syncthreads();
            mac_tile(As, Bs, ty, tx, acc);
        }
        for (int i = 0; i < 4; ++i) {
            int tr = t0 + ty * 4 + i;
            float4 o;
            o.x = acc[i][0] + bih1[n0 + tx*4 + 0] + bhh1[n0 + tx*4 + 0];
            o.y = acc[i][1] + bih1[n0 + tx*4 + 1] + bhh1[n0 + tx*4 + 1];
            o.z = acc[i][2] + bih1[n0 + tx*4 + 2] + bhh1[n0 + tx*4 + 2];
            o.w = acc[i][3] + bih1[n0 + tx*4 + 3] + bhh1[n0 + tx*4 + 3];
            *(float4*)(xg1 + (size_t)tr * 3200 + n0 + tx * 4) = o;
        }
        publish(&flags[4 + tb], tid);

    } else if (bid < 600) {
        // ---- role: LSTM layer 1 ----
        lstm_role(smem, bid - 500, Whh1, h0, c0, 2, xg1, hist1, &flags[4]);

    } else if (bid < 800) {
        // ---- role: GEMM hist1 -> PQ ----
        float (*As)[68] = (float(*)[68])smem;
        float (*Bs)[68] = (float(*)[68])(smem + 4352);
        int j = bid - 600;
        int tb = j & 3, t0 = tb * 64, n0 = (j >> 2) * 64;
        int tx = tid & 15, ty = tid >> 4, lr = tid >> 2, lk = (tid & 3) * 4;
        float acc[4][4] = {};
        int t = t0 + lr;
        int nn = n0 + lr;
        const float* brow = (nn < 1600) ? Wa1 + (size_t)nn * 1600
                                        : Wa1 + (size_t)(nn - 1600) * 1600 + 800;
        for (int k0 = 0; k0 < 800; k0 += 16) {
            float4 av = hist4_poll(hist1, t, k0 + lk);
            float4 bv = *(const float4*)(brow + k0 + lk);
            __syncthreads();
            stage_tile(As, Bs, lr, lk, av, bv);
            __syncthreads();
            mac_tile(As, Bs, ty, tx, acc);
        }
        for (int i = 0; i < 4; ++i) {
            int tr = t0 + ty * 4 + i;
            float4 o;
            int n = n0 + tx * 4;
            o.x = acc[i][0] + ((n+0 < 1600) ? ba1[n+0] : 0.f);
            o.y = acc[i][1] + ((n+1 < 1600) ? ba1[n+1] : 0.f);
            o.z = acc[i][2] + ((n+2 < 1600) ? ba1[n+2] : 0.f);
            o.w = acc[i][3] + ((n+3 < 1600) ? ba1[n+3] : 0.f);
            *(float4*)(PQ + (size_t)tr * 3200 + n) = o;
        }
        publish(&flags[8], tid);

    } else if (bid < 900) {
        // ---- role: GEMM hist1(+arc indirection) -> U (tanh) ----
        float (*As)[68] = (float(*)[68])smem;
        float (*Bs)[68] = (float(*)[68])(smem + 4352);
        int j = bid - 800;
        int tb = j & 3, t0 = tb * 64, n0 = (j >> 2) * 64;
        int tx = tid & 15, ty = tid >> 4, lr = tid >> 2, lk = (tid & 3) * 4;
        float acc[4][4] = {};
        int t = t0 + lr;
        int hh = arcs[1 + t];
        int tind = min(max(hh - 1, 0), 255);
        for (int k0 = 0; k0 < 1600; k0 += 16) {
            int k = k0 + lk;
            float4 av = (k < 800) ? hist4_poll(hist1, t, k) : hist4_poll(hist1, tind, k - 800);
            float4 bv = *(const float4*)(Wl1 + (size_t)(n0 + lr) * 1600 + k);
            __syncthreads();
            stage_tile(As, Bs, lr, lk, av, bv);
            __syncthreads();
            mac_tile(As, Bs, ty, tx, acc);
        }
        for (int i = 0; i < 4; ++i) {
            int tr = t0 + ty * 4 + i;
            int n = n0 + tx * 4;
            float4 o;
            o.x = fast_tanh(acc[i][0] + bl1[n+0]);
            o.y = fast_tanh(acc[i][1] + bl1[n+1]);
            o.z = fast_tanh(acc[i][2] + bl1[n+2]);
            o.w = fast_tanh(acc[i][3] + bl1[n+3]);
            *(float4*)(Ub + (size_t)tr * 1600 + n) = o;
        }
        publish(&flags[9 + tb], tid);

    } else if (bid < 1028) {
        // ---- role: arc scorer (16 i-rows x 32 j-cols per block) + borders ----
        float (*Pt)[65]  = (float(*)[65])smem;
        float (*Qt)[65]  = (float(*)[65])(smem + 4160);
        float* W2f       = (float*)(smem + 12480);
        int j = bid - 900;
        int i0 = (j >> 3) * 16, j0 = (j & 7) * 32;
        int ii = tid >> 4, jje = tid & 15;

        if (j == 0) {   // borders don't depend on PQ
            out[tid] = (tid == 0) ? 1.0f : 0.0f;
            if (tid == 0) out[256] = 0.0f;
            out[(size_t)(tid + 1) * 257] = 0.0f;
        }
        for (int m = tid; m < 1600; m += 256) W2f[m] = Wa2[m];
        wait_flag(&flags[8], 200u);
        __syncthreads();

        float acc0 = 0.f, acc1 = 0.f;
        int mm = tid & 63, r4 = tid >> 6;
        for (int m0 = 0; m0 < 1600; m0 += 64) {
#pragma unroll
            for (int rr = r4; rr < 16; rr += 4)
                Pt[rr][mm] = PQ[(size_t)(i0 + rr) * 3200 + m0 + mm];
#pragma unroll
            for (int rr = r4; rr < 32; rr += 4)
                Qt[rr][mm] = PQ[(size_t)(j0 + rr) * 3200 + 1600 + m0 + mm];
            __syncthreads();
#pragma unroll 4
            for (int m = 0; m < 64; ++m) {
                float p = Pt[ii][m];
                float w = W2f[m0 + m];
                acc0 += w * fast_tanh(p + Qt[jje][m]);
                acc1 += w * fast_tanh(p + Qt[jje + 16][m]);
            }
            __syncthreads();
        }
        float b2 = ba2[0];
        int gi = i0 + ii;
        int gj0 = j0 + jje, gj1 = j0 + 16 + jje;
        float raw0 = acc0 + b2, raw1 = acc1 + b2;
        if (gi == gj0) raw0 = 0.f;
        if (gi == gj1) raw1 = 0.f;
        out[(size_t)(gi + 1) * 257 + (gj0 + 1)] = raw0;
        out[(size_t)(gi + 1) * 257 + (gj1 + 1)] = raw1;

    } else {
        // ---- role: label output (4 t per block) ----
        float* u_l = (float*)smem;                 // 1600 floats
        float (*part)[64] = (float(*)[64])(smem + 6400);
        int j = bid - 1028;
        wait_flag(&flags[9 + (j >> 4)], 25u);
        for (int s = 0; s < 4; ++s) {
            int t = 4 * j + s;
            __syncthreads();
            for (int m = tid; m < 1600; m += 256) u_l[m] = Ub[(size_t)t * 1600 + m];
            __syncthreads();
            int n = tid & 63, p = tid >> 6;
            float acc = 0.f;
            if (n < 40) {
                const float4* wr4 = (const float4*)(Wl2 + (size_t)n * 1600 + p * 400);
                const float*  ub  = u_l + p * 400;
                for (int m = 0; m < 100; ++m) {
                    float4 w = wr4[m];
                    acc += ub[4*m] * w.x + ub[4*m+1] * w.y + ub[4*m+2] * w.z + ub[4*m+3] * w.w;
                }
            }
            part[p][n] = acc;
            __syncthreads();
            if (tid < 40) {
                float v = part[0][tid] + part[1][tid] + part[2][tid] + part[3][tid] + bl2[tid];
                if (arcs[1 + t] == 0) v = 0.f;
                out[66049 + (size_t)t * 40 + tid] = v;
            }
        }
    }
}

// ---------------- launch ----------------
extern "C" void kernel_launch(void* const* d_in, const int* in_sizes, int n_in,
                              void* d_out, int out_size, void* d_ws, size_t ws_size,
                              hipStream_t stream) {
    const int*   words = (const int*)d_in[0];
    const int*   tags  = (const int*)d_in[1];
    const int*   arcs  = (const int*)d_in[2];
    const float* h0    = (const float*)d_in[3];
    const float* c0    = (const float*)d_in[4];
    const float* wemb  = (const float*)d_in[5];
    const float* temb  = (const float*)d_in[6];
    const float* Wih0  = (const float*)d_in[7];
    const float* Whh0  = (const float*)d_in[8];
    const float* bih0  = (const float*)d_in[9];
    const float* bhh0  = (const float*)d_in[10];
    const float* Wih1  = (const float*)d_in[11];
    const float* Whh1  = (const float*)d_in[12];
    const float* bih1  = (const float*)d_in[13];
    const float* bhh1  = (const float*)d_in[14];
    const float* Wa1   = (const float*)d_in[15];
    const float* ba1   = (const float*)d_in[16];
    const float* Wa2   = (const float*)d_in[17];
    const float* ba2   = (const float*)d_in[18];
    const float* Wl1   = (const float*)d_in[19];
    const float* bl1   = (const float*)d_in[20];
    const float* Wl2   = (const float*)d_in[21];
    const float* bl2   = (const float*)d_in[22];
    float* out = (float*)d_out;

    char* ws = (char*)d_ws;
    float* xg0   = (float*)(ws + OF_XG0);
    float* xg1   = (float*)(ws + OF_XG1);
    u64*   hist0 = (u64*)  (ws + OF_H0);
    u64*   hist1 = (u64*)  (ws + OF_H1);
    float* PQ    = (float*)(ws + OF_PQ);
    float* Ub    = (float*)(ws + OF_U);
    u32*   flags = (u32*)  (ws + OF_FLG);

    hipMemsetAsync(flags, 0, 64, stream);
    mega_kernel<<<1092, 256, 18944, stream>>>(
        words, tags, arcs, h0, c0, wemb, temb,
        Wih0, Whh0, bih0, bhh0, Wih1, Whh1, bih1, bhh1,
        Wa1, ba1, Wa2, ba2, Wl1, bl1, Wl2, bl2,
        xg0, xg1, hist0, hist1, PQ, Ub, flags, out);
}